// Round 6
// baseline (228.311 us; speedup 1.0000x reference)
//
#include <hip/hip_runtime.h>

typedef unsigned short u16;
typedef unsigned int u32;
typedef unsigned long long u64;
typedef __attribute__((ext_vector_type(4))) float f32x4;
typedef __attribute__((ext_vector_type(4))) unsigned short u16x4;
typedef __attribute__((ext_vector_type(8))) short short8;

#define GLOAD16(G, L) __builtin_amdgcn_global_load_lds( \
    (const __attribute__((address_space(1))) void*)(G), \
    (__attribute__((address_space(3))) void*)(L), 16, 0, 0)

__device__ __forceinline__ u16 f2bf(float f) {
  union { float f; unsigned u; } c; c.f = f;
  unsigned u = c.u;
  u += 0x7FFFu + ((u >> 16) & 1u);
  return (u16)(u >> 16);
}

__device__ __forceinline__ void store_out(u16* p, float v) { *p = f2bf(v); }
__device__ __forceinline__ void store_out(float* p, float v) { *p = v; }

// ---------- elementwise f32 -> bf16 ----------
__global__ void k_cvt(const float* __restrict__ in, u16* __restrict__ out, int n4) {
  int i = blockIdx.x * blockDim.x + threadIdx.x;
  if (i >= n4) return;
  const f32x4 v = *(const f32x4*)(in + (size_t)i * 4);
  u16x4 o;
  o[0] = f2bf(v[0]); o[1] = f2bf(v[1]); o[2] = f2bf(v[2]); o[3] = f2bf(v[3]);
  *(u16x4*)(out + (size_t)i * 4) = o;
}

// ---------- transpose+convert+scale: src[R][C] f32 -> dst[C][R] bf16 ----------
__global__ void k_tcvt(const float* __restrict__ src, u16* __restrict__ dst,
                       int R, int C, float scale) {
  __shared__ float t[32][33];
  int bx = blockIdx.x * 32;
  int by = blockIdx.y * 32;
  int tx = threadIdx.x, ty = threadIdx.y;
  #pragma unroll
  for (int j = 0; j < 32; j += 8)
    t[ty + j][tx] = src[(size_t)(by + ty + j) * C + bx + tx];
  __syncthreads();
  #pragma unroll
  for (int j = 0; j < 32; j += 8)
    dst[(size_t)(bx + ty + j) * R + by + tx] = f2bf(t[tx][ty + j] * scale);
}

// ---------- transpose V with k-permutation ----------
// vt[b*1024 + d][tblk*64 + i(k)] = kv[b*2048 + t][1024 + d],  k = t & 63,
// i(k) = ((k>>2)&3)*16 + (k>>4)*4 + (k&3)  (so PV fragments are 16B-contiguous)
__global__ void k_tv(const u16* __restrict__ kv, u16* __restrict__ vt) {
  __shared__ u16 sh[32][34];
  int b = blockIdx.z;
  int tb = blockIdx.x * 32;
  int db = blockIdx.y * 32;
  int tx = threadIdx.x, ty = threadIdx.y;
  #pragma unroll
  for (int j = 0; j < 32; j += 8)
    sh[ty + j][tx] = kv[(size_t)(b * 2048 + tb + ty + j) * 2048 + 1024 + db + tx];
  __syncthreads();
  int t = tb + tx;
  int k6 = t & 63;
  int colp = (t & ~63) | (((k6 >> 2) & 3) << 4) | ((k6 >> 4) << 2) | (k6 & 3);
  #pragma unroll
  for (int j = 0; j < 32; j += 8)
    vt[(size_t)(b * 1024 + db + ty + j) * 2048 + colp] = sh[tx][ty + j];
}

// ---------- pack mask into bits: bits[(b*2048+q)*64 + k/32] ----------
__global__ void k_pm(const int* __restrict__ mask, unsigned* __restrict__ bits, int nw) {
  int w = blockIdx.x * blockDim.x + threadIdx.x;
  if (w >= nw) return;
  const int4* p = (const int4*)(mask + (size_t)w * 32);
  unsigned b = 0;
  #pragma unroll
  for (int j = 0; j < 8; ++j) {
    int4 v = p[j];
    b |= (v.x != 0 ? 1u : 0u) << (j * 4);
    b |= (v.y != 0 ? 1u : 0u) << (j * 4 + 1);
    b |= (v.z != 0 ? 1u : 0u) << (j * 4 + 2);
    b |= (v.w != 0 ? 1u : 0u) << (j * 4 + 3);
  }
  bits[w] = b;
}

// ---------- bf16 GEMM: C[M][N] = A[M][K] @ Bt[N][K]^T, tile BM x BN, BK=64 ----------
template <int BM, int BN, typename OUT_T>
__global__ __launch_bounds__(256) void k_gemm(
    const u16* __restrict__ A, const u16* __restrict__ Bt,
    OUT_T* __restrict__ C, int M, int N, int K)
{
  constexpr int MI = BM / 32, NI = BN / 32;
  __shared__ u16 As[BM * 64];
  __shared__ u16 Bs[BN * 64];
  const int tid = threadIdx.x;
  const int lane = tid & 63;
  const int w = tid >> 6;
  const int wr = w >> 1, wc = w & 1;
  const int l16 = lane & 15, lh = lane >> 4;
  const size_t tm = blockIdx.x, tn = blockIdx.y;

  f32x4 acc[MI][NI] = {};

  for (int kt = 0; kt < K; kt += 64) {
    #pragma unroll
    for (int i = 0; i < BM / 32; ++i) {
      int flat = i * 256 + tid;
      int row = flat >> 3, cb = flat & 7;
      GLOAD16(A + (tm * BM + row) * K + kt + ((cb ^ (row & 7)) * 8),
              (char*)As + flat * 16);
    }
    #pragma unroll
    for (int i = 0; i < BN / 32; ++i) {
      int flat = i * 256 + tid;
      int row = flat >> 3, cb = flat & 7;
      GLOAD16(Bt + (tn * BN + row) * K + kt + ((cb ^ (row & 7)) * 8),
              (char*)Bs + flat * 16);
    }
    __syncthreads();
    #pragma unroll
    for (int kk = 0; kk < 2; ++kk) {
      short8 a[MI], b[NI];
      #pragma unroll
      for (int mi = 0; mi < MI; ++mi) {
        int row = wr * (BM / 2) + mi * 16 + l16;
        a[mi] = *(const short8*)&As[row * 64 + ((kk * 32 + lh * 8) ^ ((row & 7) * 8))];
      }
      #pragma unroll
      for (int ni = 0; ni < NI; ++ni) {
        int row = wc * (BN / 2) + ni * 16 + l16;
        b[ni] = *(const short8*)&Bs[row * 64 + ((kk * 32 + lh * 8) ^ ((row & 7) * 8))];
      }
      #pragma unroll
      for (int mi = 0; mi < MI; ++mi)
        #pragma unroll
        for (int ni = 0; ni < NI; ++ni)
          acc[mi][ni] = __builtin_amdgcn_mfma_f32_16x16x32_bf16(a[mi], b[ni], acc[mi][ni], 0, 0, 0);
    }
    __syncthreads();
  }
  #pragma unroll
  for (int mi = 0; mi < MI; ++mi)
    #pragma unroll
    for (int ni = 0; ni < NI; ++ni)
      #pragma unroll
      for (int r = 0; r < 4; ++r) {
        size_t row = tm * BM + wr * (BM / 2) + mi * 16 + lh * 4 + r;
        size_t col = tn * BN + wc * (BN / 2) + ni * 16 + l16;
        store_out(&C[row * N + col], acc[mi][ni][r]);
      }
}

// ---------- fused flash attention, S^T, q=32/wave, counted-vmcnt pipeline ----------
// grid (qt=32, h=16), 256 threads = 4 waves; wave w: batch = w>>1, q-base (w&1)*32.
// Each wave computes 32 q-rows: K/V fragments read from LDS ONCE, used for both
// q-halves -> LDS read traffic per unit work halved vs 16-q waves.
__global__ __launch_bounds__(256, 2) void k_attn(
    const u16* __restrict__ Qp,      // [4096][1024], pre-scaled by 1/8
    const u16* __restrict__ KVp,     // [4096][2048] (cols 0..1023 = K heads)
    const u16* __restrict__ Vt,      // [2048][2048] permuted (see k_tv)
    const float* __restrict__ bias,  // [16][2048][2048]
    const unsigned* __restrict__ mbits, // [2][2048][64]
    u16* __restrict__ Ob)            // [4096][1024]
{
  __shared__ u16 Ks[2 * 2 * 64 * 64];  // [buf][batch][k-row][d]  32 KB, 16B-XOR
  __shared__ u16 Vs[2 * 2 * 64 * 64];  // [buf][batch][d-row][i]  32 KB, 16B-XOR
  const int tid = threadIdx.x;         // 0..255
  const int lane = tid & 63;
  const int w = tid >> 6;              // 0..3
  const int bw = w >> 1;               // batch
  const int qs = (w & 1) * 32;         // q offset within 64-row tile
  const int qt = blockIdx.x;
  const int h  = blockIdx.y;
  const int l16 = lane & 15, lh = lane >> 4;
  const int q0 = qt * 64 + qs + l16;   // first q-half row
  // q1 = q0 + 16

  // staging geometry: 2 chunks of 16B per thread per (tensor,batch)
  const int sr0 = tid >> 3;
  const int sc0 = (((tid & 7)) ^ (sr0 & 7)) * 8;
  const int sr1 = (256 + tid) >> 3;
  const int sc1 = ((((256 + tid) & 7)) ^ (sr1 & 7)) * 8;
  const u16* k0 = KVp + (size_t)sr0 * 2048 + h * 64 + sc0;
  const u16* k1 = KVp + (size_t)sr1 * 2048 + h * 64 + sc1;
  const u16* v0 = Vt + (size_t)(h * 64 + sr0) * 2048 + sc0;
  const u16* v1 = Vt + (size_t)(h * 64 + sr1) * 2048 + sc1;

  // Q fragments for both q-halves
  short8 qf0[2], qf1[2];
  {
    size_t row = (size_t)bw * 2048 + q0;
    qf0[0] = *(const short8*)&Qp[row * 1024 + h * 64 + lh * 8];
    qf0[1] = *(const short8*)&Qp[row * 1024 + h * 64 + 32 + lh * 8];
    qf1[0] = *(const short8*)&Qp[(row + 16) * 1024 + h * 64 + lh * 8];
    qf1[1] = *(const short8*)&Qp[(row + 16) * 1024 + h * 64 + 32 + lh * 8];
  }

  const float* bsrc0 = bias + ((size_t)h * 2048 + q0) * 2048 + lh * 4;
  const float* bsrc1 = bsrc0 + (size_t)16 * 2048;
  const u64* msrc0 = (const u64*)(mbits + ((size_t)bw * 2048 + q0) * 64);
  const u64* msrc1 = msrc0 + 16 * 32;

  f32x4 oacc0[4] = {}, oacc1[4] = {};
  f32x4 lpv0 = {}, lpv1 = {};
  f32x4 bA0[4], bA1[4], bB0[4], bB1[4];
  u64 mA0, mA1, mB0, mB1;

  // ---- prologue: stage kt=0 -> buf0; bias/mask kt=0 -> set A ----
  GLOAD16(k0,                       &Ks[tid * 8]);
  GLOAD16(k1,                       &Ks[2048 + tid * 8]);
  GLOAD16(k0 + (size_t)2048 * 2048, &Ks[4096 + tid * 8]);
  GLOAD16(k1 + (size_t)2048 * 2048, &Ks[6144 + tid * 8]);
  GLOAD16(v0,                       &Vs[tid * 8]);
  GLOAD16(v1,                       &Vs[2048 + tid * 8]);
  GLOAD16(v0 + (size_t)1024 * 2048, &Vs[4096 + tid * 8]);
  GLOAD16(v1 + (size_t)1024 * 2048, &Vs[6144 + tid * 8]);
  #pragma unroll
  for (int ni = 0; ni < 4; ++ni) {
    bA0[ni] = *(const f32x4*)(bsrc0 + ni * 16);
    bA1[ni] = *(const f32x4*)(bsrc1 + ni * 16);
  }
  mA0 = msrc0[0];
  mA1 = msrc1[0];
  asm volatile("s_waitcnt vmcnt(0)" ::: "memory");
  __builtin_amdgcn_s_barrier();

#define ASTEP(KT, CUR, BC0, BC1, MC0, MC1, BN0, BN1, MN0, MN1) do {                      \
    const int ktn_ = ((KT) + 1 < 32) ? (KT) + 1 : 31;                                    \
    const int nb_ = (CUR) ^ 1;                                                           \
    GLOAD16(k0 + (size_t)ktn_ * 64 * 2048,                  &Ks[nb_ * 8192 + tid * 8]);  \
    GLOAD16(k1 + (size_t)ktn_ * 64 * 2048,                  &Ks[nb_ * 8192 + 2048 + tid * 8]); \
    GLOAD16(k0 + ((size_t)2048 + ktn_ * 64) * 2048,         &Ks[nb_ * 8192 + 4096 + tid * 8]); \
    GLOAD16(k1 + ((size_t)2048 + ktn_ * 64) * 2048,         &Ks[nb_ * 8192 + 6144 + tid * 8]); \
    GLOAD16(v0 + (size_t)ktn_ * 64,                         &Vs[nb_ * 8192 + tid * 8]);  \
    GLOAD16(v1 + (size_t)ktn_ * 64,                         &Vs[nb_ * 8192 + 2048 + tid * 8]); \
    GLOAD16(v0 + (size_t)1024 * 2048 + ktn_ * 64,           &Vs[nb_ * 8192 + 4096 + tid * 8]); \
    GLOAD16(v1 + (size_t)1024 * 2048 + ktn_ * 64,           &Vs[nb_ * 8192 + 6144 + tid * 8]); \
    __builtin_amdgcn_sched_barrier(0);                                                   \
    f32x4 s0_[4], s1_[4];                                                                \
    _Pragma("unroll")                                                                    \
    for (int ni = 0; ni < 4; ++ni) { s0_[ni] = BC0[ni]; s1_[ni] = BC1[ni]; }             \
    const unsigned tlo0_ = (unsigned)(MC0) >> (lh * 4);                                  \
    const unsigned thi0_ = (unsigned)((MC0) >> 32) >> (lh * 4);                          \
    const unsigned tlo1_ = (unsigned)(MC1) >> (lh * 4);                                  \
    const unsigned thi1_ = (unsigned)((MC1) >> 32) >> (lh * 4);                          \
    _Pragma("unroll")                                                                    \
    for (int ni = 0; ni < 4; ++ni) {                                                     \
      BN0[ni] = *(const f32x4*)(bsrc0 + (size_t)ktn_ * 64 + ni * 16);                    \
      BN1[ni] = *(const f32x4*)(bsrc1 + (size_t)ktn_ * 64 + ni * 16);                    \
    }                                                                                    \
    MN0 = msrc0[ktn_];                                                                   \
    MN1 = msrc1[ktn_];                                                                   \
    const int kb_ = (CUR) * 8192 + bw * 4096;                                            \
    __builtin_amdgcn_s_setprio(1);                                                       \
    _Pragma("unroll")                                                                    \
    for (int kk = 0; kk < 2; ++kk) {                                                     \
      short8 kf_[4];                                                                     \
      _Pragma("unroll")                                                                  \
      for (int ni = 0; ni < 4; ++ni) {                                                   \
        const int row_ = ni * 16 + l16;                                                  \
        kf_[ni] = *(const short8*)&Ks[kb_ + row_ * 64 + ((kk * 32 + lh * 8) ^ ((row_ & 7) * 8))]; \
      }                                                                                  \
      _Pragma("unroll")                                                                  \
      for (int ni = 0; ni < 4; ++ni) {                                                   \
        s0_[ni] = __builtin_amdgcn_mfma_f32_16x16x32_bf16(kf_[ni], qf0[kk], s0_[ni], 0, 0, 0); \
        s1_[ni] = __builtin_amdgcn_mfma_f32_16x16x32_bf16(kf_[ni], qf1[kk], s1_[ni], 0, 0, 0); \
      }                                                                                  \
    }                                                                                    \
    __builtin_amdgcn_s_setprio(0);                                                       \
    union pfu_ { u32 wd[4]; short8 v; };                                                 \
    union pfu_ pf0_[2], pf1_[2];                                                         \
    _Pragma("unroll")                                                                    \
    for (int ni = 0; ni < 4; ++ni) {                                                     \
      const unsigned tw0_ = (ni < 2) ? tlo0_ : thi0_;                                    \
      const unsigned tw1_ = (ni < 2) ? tlo1_ : thi1_;                                    \
      _Pragma("unroll")                                                                  \
      for (int r = 0; r < 4; ++r) {                                                      \
        const unsigned b0_ = (tw0_ >> ((ni & 1) * 16 + r)) & 1u;                         \
        const unsigned b1_ = (tw1_ >> ((ni & 1) * 16 + r)) & 1u;                         \
        s0_[ni][r] = b0_ ? __expf(s0_[ni][r]) : 0.f;                                     \
        s1_[ni][r] = b1_ ? __expf(s1_[ni][r]) : 0.f;                                     \
      }                                                                                  \
      lpv0 += s0_[ni];                                                                   \
      lpv1 += s1_[ni];                                                                   \
      asm("v_cvt_pk_bf16_f32 %0, %1, %2" : "=v"(pf0_[ni >> 1].wd[2 * (ni & 1)])     : "v"(s0_[ni][0]), "v"(s0_[ni][1])); \
      asm("v_cvt_pk_bf16_f32 %0, %1, %2" : "=v"(pf0_[ni >> 1].wd[2 * (ni & 1) + 1]) : "v"(s0_[ni][2]), "v"(s0_[ni][3])); \
      asm("v_cvt_pk_bf16_f32 %0, %1, %2" : "=v"(pf1_[ni >> 1].wd[2 * (ni & 1)])     : "v"(s1_[ni][0]), "v"(s1_[ni][1])); \
      asm("v_cvt_pk_bf16_f32 %0, %1, %2" : "=v"(pf1_[ni >> 1].wd[2 * (ni & 1) + 1]) : "v"(s1_[ni][2]), "v"(s1_[ni][3])); \
    }                                                                                    \
    __builtin_amdgcn_s_setprio(1);                                                       \
    _Pragma("unroll")                                                                    \
    for (int kk = 0; kk < 2; ++kk) {                                                     \
      _Pragma("unroll")                                                                  \
      for (int di = 0; di < 4; ++di) {                                                   \
        const int row_ = di * 16 + l16;                                                  \
        short8 vf_ = *(const short8*)&Vs[kb_ + row_ * 64 + (((lh * 2 + kk) * 8) ^ ((row_ & 7) * 8))]; \
        oacc0[di] = __builtin_amdgcn_mfma_f32_16x16x32_bf16(vf_, pf0_[kk].v, oacc0[di], 0, 0, 0); \
        oacc1[di] = __builtin_amdgcn_mfma_f32_16x16x32_bf16(vf_, pf1_[kk].v, oacc1[di], 0, 0, 0); \
      }                                                                                  \
    }                                                                                    \
    __builtin_amdgcn_s_setprio(0);                                                       \
    asm volatile("s_waitcnt lgkmcnt(0)" ::: "memory");                                   \
    asm volatile("s_waitcnt vmcnt(10)" ::: "memory");                                    \
    __builtin_amdgcn_s_barrier();                                                        \
  } while (0)

  for (int kt2 = 0; kt2 < 32; kt2 += 2) {
    ASTEP(kt2,     0, bA0, bA1, mA0, mA1, bB0, bB1, mB0, mB1);
    ASTEP(kt2 + 1, 1, bB0, bB1, mB0, mB1, bA0, bA1, mA0, mA1);
  }
#undef ASTEP

  // ---- epilogue: reduce row-sums across lh groups, divide, pack, store ----
  {
    float lp = lpv0[0] + lpv0[1] + lpv0[2] + lpv0[3];
    lp += __shfl_xor(lp, 16);
    lp += __shfl_xor(lp, 32);
    float inv = 1.0f / lp;
    size_t orow = (size_t)bw * 2048 + q0;
    #pragma unroll
    for (int di = 0; di < 4; ++di)
      #pragma unroll
      for (int rp = 0; rp < 2; ++rp) {
        float a = oacc0[di][2 * rp] * inv;
        float b = oacc0[di][2 * rp + 1] * inv;
        u32 pk;
        asm("v_cvt_pk_bf16_f32 %0, %1, %2" : "=v"(pk) : "v"(a), "v"(b));
        *(u32*)&Ob[orow * 1024 + h * 64 + di * 16 + lh * 4 + rp * 2] = pk;
      }
  }
  {
    float lp = lpv1[0] + lpv1[1] + lpv1[2] + lpv1[3];
    lp += __shfl_xor(lp, 16);
    lp += __shfl_xor(lp, 32);
    float inv = 1.0f / lp;
    size_t orow = (size_t)bw * 2048 + q0 + 16;
    #pragma unroll
    for (int di = 0; di < 4; ++di)
      #pragma unroll
      for (int rp = 0; rp < 2; ++rp) {
        float a = oacc1[di][2 * rp] * inv;
        float b = oacc1[di][2 * rp + 1] * inv;
        u32 pk;
        asm("v_cvt_pk_bf16_f32 %0, %1, %2" : "=v"(pk) : "v"(a), "v"(b));
        *(u32*)&Ob[orow * 1024 + h * 64 + di * 16 + lh * 4 + rp * 2] = pk;
      }
  }
}

extern "C" void kernel_launch(void* const* d_in, const int* in_sizes, int n_in,
                              void* d_out, int out_size, void* d_ws, size_t ws_size,
                              hipStream_t stream) {
  const float* query     = (const float*)d_in[0];
  const float* key_value = (const float*)d_in[1];
  const int*   mask      = (const int*)d_in[2];
  const float* bias      = (const float*)d_in[3];
  const float* Wq        = (const float*)d_in[4];
  const float* Wkv       = (const float*)d_in[5];
  const float* Wo        = (const float*)d_in[6];
  float* out = (float*)d_out;

  char* ws = (char*)d_ws;
  u16* qb   = (u16*)(ws);                    // 8 MiB  bf16 query
  u16* kvb  = (u16*)(ws + 8388608);          // 8 MiB  bf16 key_value
  u16* WqT  = (u16*)(ws + 16777216);         // 2 MiB  Wq^T * 0.125
  u16* WkvT = (u16*)(ws + 18874368);         // 4 MiB  Wkv^T
  u16* WoT  = (u16*)(ws + 23068672);         // 2 MiB  Wo^T
  u16* Qp   = (u16*)(ws + 25165824);         // 8 MiB  projected q
  u16* KVp  = (u16*)(ws + 33554432);         // 16 MiB projected kv
  u16* Vt   = (u16*)(ws + 50331648);         // 8 MiB  V transposed+permuted
  u16* Ob   = (u16*)(ws + 58720256);         // 8 MiB  attention out
  unsigned* mb = (unsigned*)(ws + 67108864); // 1 MiB  packed mask

  dim3 tb(32, 8);
  k_cvt<<<4096, 256, 0, stream>>>(query, qb, 1048576);
  k_cvt<<<4096, 256, 0, stream>>>(key_value, kvb, 1048576);
  k_tcvt<<<dim3(32, 32), tb, 0, stream>>>(Wq,  WqT,  1024, 1024, 0.125f);
  k_tcvt<<<dim3(64, 32), tb, 0, stream>>>(Wkv, WkvT, 1024, 2048, 1.0f);
  k_tcvt<<<dim3(32, 32), tb, 0, stream>>>(Wo,  WoT,  1024, 1024, 1.0f);
  k_pm<<<1024, 256, 0, stream>>>(mask, mb, 262144);
  k_gemm<64, 128, u16><<<dim3(64, 8),  256, 0, stream>>>(qb,  WqT,  Qp,  4096, 1024, 1024);
  k_gemm<64, 128, u16><<<dim3(64, 16), 256, 0, stream>>>(kvb, WkvT, KVp, 4096, 2048, 1024);
  k_tv<<<dim3(64, 32, 2), tb, 0, stream>>>(KVp, Vt);
  k_attn<<<dim3(32, 16), 256, 0, stream>>>(Qp, KVp, Vt, bias, mb, Ob);
  k_gemm<64, 128, float><<<dim3(64, 8), 256, 0, stream>>>(Ob, WoT, out, 4096, 1024, 1024);
}